// Round 2
// baseline (11066.695 us; speedup 1.0000x reference)
//
#include <hip/hip_runtime.h>
#include <hip/hip_bf16.h>

using short8 = __attribute__((ext_vector_type(8))) short;
using f32x4  = __attribute__((ext_vector_type(4))) float;
typedef unsigned short u16;
typedef unsigned int u32;

#define S_LEN 256
#define BATCH 128
#define HID   512
#define GATE  1536
#define SB    32768   // S_LEN*BATCH

static __device__ __forceinline__ u16 f2b(float f){
  union { float f; u32 u; } v; v.f = f;
  u32 r = v.u + 0x7fffu + ((v.u >> 16) & 1u);
  return (u16)(r >> 16);
}
static __device__ __forceinline__ float b2f(u16 h){
  union { u32 u; float f; } v; v.u = ((u32)h) << 16; return v.f;
}
static __device__ __forceinline__ f32x4 mfma16(short8 a, short8 b, f32x4 c){
  return __builtin_amdgcn_mfma_f32_16x16x32_bf16(a, b, c, 0, 0, 0);
}

// ---------------- utility kernels ----------------

__global__ void fill_zero(float* p, long n){
  long i = (long)blockIdx.x * blockDim.x + threadIdx.x;
  long st = (long)gridDim.x * blockDim.x;
  for (; i < n; i += st) p[i] = 0.f;
}

__global__ void copy_f32(const float* src, float* dst, long n){
  long i = (long)blockIdx.x * blockDim.x + threadIdx.x;
  long st = (long)gridDim.x * blockDim.x;
  for (; i < n; i += st) dst[i] = src[i];
}

__global__ void cvt_bf16(const float* in, u16* out, long n){
  long i = (long)blockIdx.x * blockDim.x + threadIdx.x;
  long st = (long)gridDim.x * blockDim.x;
  for (; i < n; i += st) out[i] = f2b(in[i]);
}

// gate-row permutation: old row = g*512 + c  ->  new row = 48*(c>>4) + 16*g + (c&15)
__global__ void permute_rows(const float* in, u16* out, int K){
  long n = (long)GATE * K;
  long i = (long)blockIdx.x * blockDim.x + threadIdx.x;
  long st = (long)gridDim.x * blockDim.x;
  for (; i < n; i += st){
    int orow = (int)(i / K); int k = (int)(i - (long)orow * K);
    int g = orow >> 9, c = orow & 511;
    int nrow = ((c >> 4) * 48) + (g << 4) + (c & 15);
    out[(long)nrow * K + k] = f2b(in[i]);
  }
}

__global__ void permute_bias(const float* in, float* out){
  int orow = blockIdx.x * blockDim.x + threadIdx.x;
  if (orow < GATE){
    int g = orow >> 9, c = orow & 511;
    out[((c >> 4) * 48) + (g << 4) + (c & 15)] = in[orow];
  }
}

// x0[s*B+b][0:128]=emb1[i1], [128:192]=emb2[i2] (0 if idx==0), bf16
__global__ void embed_kernel(const int* __restrict__ i1, const int* __restrict__ i2,
                             const float* __restrict__ e1, const float* __restrict__ e2,
                             u16* __restrict__ x0){
  int row = blockIdx.x; int t = threadIdx.x;
  float v;
  if (t < 128) v = e1[(long)i1[row] * 128 + t];
  else { int ix = i2[row]; v = ix ? e2[(long)ix * 64 + (t - 128)] : 0.f; }
  x0[(long)row * 192 + t] = f2b(v);
}

// ---------------- generic bf16 MFMA GEMM: C = A[M,K] * W[N,K]^T (+bias)(+relu) ----------------
// grid (M/128, N/128, Z); block 256 (4 waves, each 64x64 of the 128x128 C-tile)
__global__ __launch_bounds__(256) void gemm_bt(
    const u16* __restrict__ A, int lda, long sAz,
    const u16* __restrict__ W, int ldw, long sWz,
    const float* __restrict__ bias,
    u16* __restrict__ Cb, int ldc, long sCz,
    float* __restrict__ Cf,       // optional f32 out, (b,s)->(s,b) transposed, ld 512
    int K, int flags)             // bit0 = relu
{
  __shared__ u16 As[128 * 40];
  __shared__ u16 Ws[128 * 40];
  const int tid = threadIdx.x;
  const int m0 = blockIdx.x * 128, n0 = blockIdx.y * 128;
  const long z = blockIdx.z;
  const u16* Ab = A + z * sAz;
  const u16* Wb = W + z * sWz;
  const int r0 = tid >> 2, kg = (tid & 3) * 8;   // each thread: 2 rows x 8 elems
  const int lane = tid & 63, w = tid >> 6;
  const int wr = w >> 1, wc = w & 1;
  const int col = lane & 15, q = lane >> 4;
  f32x4 acc[4][4];
#pragma unroll
  for (int i = 0; i < 4; i++)
#pragma unroll
    for (int j = 0; j < 4; j++) acc[i][j] = (f32x4){0.f, 0.f, 0.f, 0.f};

  for (int k0 = 0; k0 < K; k0 += 32){
    uint4 a0 = *(const uint4*)(Ab + (long)(m0 + r0) * lda + k0 + kg);
    uint4 a1 = *(const uint4*)(Ab + (long)(m0 + r0 + 64) * lda + k0 + kg);
    uint4 w0 = *(const uint4*)(Wb + (long)(n0 + r0) * ldw + k0 + kg);
    uint4 w1 = *(const uint4*)(Wb + (long)(n0 + r0 + 64) * ldw + k0 + kg);
    __syncthreads();
    *(uint4*)(As + r0 * 40 + kg) = a0;
    *(uint4*)(As + (r0 + 64) * 40 + kg) = a1;
    *(uint4*)(Ws + r0 * 40 + kg) = w0;
    *(uint4*)(Ws + (r0 + 64) * 40 + kg) = w1;
    __syncthreads();
    short8 af[4], bf[4];
#pragma unroll
    for (int i = 0; i < 4; i++) af[i] = *(const short8*)(As + (wr * 64 + i * 16 + col) * 40 + q * 8);
#pragma unroll
    for (int j = 0; j < 4; j++) bf[j] = *(const short8*)(Ws + (wc * 64 + j * 16 + col) * 40 + q * 8);
#pragma unroll
    for (int i = 0; i < 4; i++)
#pragma unroll
      for (int j = 0; j < 4; j++)
        acc[i][j] = mfma16(af[i], bf[j], acc[i][j]);
  }

#pragma unroll
  for (int i = 0; i < 4; i++)
#pragma unroll
    for (int j = 0; j < 4; j++){
      int n = n0 + wc * 64 + j * 16 + col;
      float bv = bias ? bias[n] : 0.f;
#pragma unroll
      for (int r = 0; r < 4; r++){
        int m = m0 + wr * 64 + i * 16 + q * 4 + r;
        float v = acc[i][j][r] + bv;
        if (flags & 1) v = fmaxf(v, 0.f);
        if (Cb) Cb[z * sCz + (long)m * ldc + n] = f2b(v);
        if (Cf){ int s = m & 255, b = m >> 8; Cf[((long)s * 128 + b) * 512 + n] = v; }
      }
    }
}

// ---------------- GRU recurrent step ----------------
// grid (32 channel-blocks, 4 batch-tiles of 32, 2 dirs); block = 64 (1 wave)
// weights gate-permuted so one wave's 3 N-tiles (r,z,n) cover the same 16 channels.
__global__ __launch_bounds__(64) void gru_step(
    const u16* __restrict__ whh,    // [2][GATE*HID] permuted bf16 (dirs adjacent)
    const float* __restrict__ bhh,  // [2][GATE] permuted
    const u16* __restrict__ xg,     // [2][SB*GATE] bf16 (permuted cols)
    const float* __restrict__ hin,  // [2][BATCH*HID] parity buffer (read)
    float* __restrict__ hout,       // [2][BATCH*HID] parity buffer (write)
    u16* __restrict__ y_cat,        // layer0: x1 concat out [SB,1024] bf16 (seq-major), else null
    u16* __restrict__ y_node,       // layer1: cat0 [b][s][dir*512+c] bf16 per-dir halves, else null
    int step)
{
  const int dir = blockIdx.z;
  const int t = dir ? (255 - step) : step;
  const u16* Wd = whh + (long)dir * GATE * HID;
  const u16* xgd = xg + (long)dir * SB * GATE;
  const float* hi = hin + dir * BATCH * HID;
  float* ho = hout + dir * BATCH * HID;
  const float* bh = bhh + dir * GATE;
  const int lane = threadIdx.x, col = lane & 15, q = lane >> 4;
  const int cb = blockIdx.x, b0 = blockIdx.y * 32;

  f32x4 acc[2][3];
#pragma unroll
  for (int ii = 0; ii < 2; ii++)
#pragma unroll
    for (int g = 0; g < 3; g++) acc[ii][g] = (f32x4){0.f, 0.f, 0.f, 0.f};

  for (int kk = 0; kk < HID; kk += 32){
    short8 af[2];
#pragma unroll
    for (int ii = 0; ii < 2; ii++){
      const float* hp = hi + (long)(b0 + ii * 16 + col) * HID + kk + q * 8;
      float4 f0 = *(const float4*)hp;
      float4 f1 = *(const float4*)(hp + 4);
      union { short8 s; u16 u[8]; } a;
      a.u[0] = f2b(f0.x); a.u[1] = f2b(f0.y); a.u[2] = f2b(f0.z); a.u[3] = f2b(f0.w);
      a.u[4] = f2b(f1.x); a.u[5] = f2b(f1.y); a.u[6] = f2b(f1.z); a.u[7] = f2b(f1.w);
      af[ii] = a.s;
    }
#pragma unroll
    for (int g = 0; g < 3; g++){
      short8 bfr = *(const short8*)(Wd + (long)(48 * cb + 16 * g + col) * HID + kk + q * 8);
      acc[0][g] = mfma16(af[0], bfr, acc[0][g]);
      acc[1][g] = mfma16(af[1], bfr, acc[1][g]);
    }
  }

  const int c = cb * 16 + col;
  const float bhr = bh[48 * cb + col];
  const float bhz = bh[48 * cb + 16 + col];
  const float bhn = bh[48 * cb + 32 + col];
#pragma unroll
  for (int ii = 0; ii < 2; ii++)
#pragma unroll
    for (int r = 0; r < 4; r++){
      int b = b0 + ii * 16 + q * 4 + r;
      long xb = ((long)t * BATCH + b) * GATE + 48 * cb;
      float xr = b2f(xgd[xb + col]);
      float xz = b2f(xgd[xb + 16 + col]);
      float xn = b2f(xgd[xb + 32 + col]);
      float gr = 1.f / (1.f + expf(-(xr + acc[ii][0][r] + bhr)));
      float gz = 1.f / (1.f + expf(-(xz + acc[ii][1][r] + bhz)));
      float gn = tanhf(xn + gr * (acc[ii][2][r] + bhn));
      float hold = hi[(long)b * HID + c];
      float hnew = (1.f - gz) * gn + gz * hold;
      ho[(long)b * HID + c] = hnew;
      if (y_cat) y_cat[((long)t * BATCH + b) * 1024 + dir * HID + c] = f2b(hnew);
      if (y_node) y_node[((long)b * 256 + t) * 1024 + dir * HID + c] = f2b(hnew);
    }
}

// cat[row][c] += cat[row][512+c] (both bf16), node = yf + yb
__global__ void combine_cat(u16* __restrict__ cat){
  long n = (long)SB * HID;
  long i = (long)blockIdx.x * blockDim.x + threadIdx.x;
  long st = (long)gridDim.x * blockDim.x;
  for (; i < n; i += st){
    long row = i >> 9; int c = (int)(i & 511);
    u16* p = cat + row * 1024;
    p[c] = f2b(b2f(p[c]) + b2f(p[512 + c]));
  }
}

// ---------------- GNN prep ----------------

__global__ __launch_bounds__(64) void deg_kernel(const int* __restrict__ pg, float* __restrict__ dinv){
  int i = blockIdx.x, b = blockIdx.y, lane = threadIdx.x;
  const int* p = pg + ((long)b * 3 + 2) * 65536 + i * 256 + lane * 4;
  int4 v = *(const int4*)p;
  int s = v.x + v.y + v.z + v.w;
  for (int o = 32; o; o >>= 1) s += __shfl_down(s, o);
  if (lane == 0) dinv[b * 256 + i] = 1.f / sqrtf((float)(s + 1));
}

__global__ void an_kernel(const int* __restrict__ pg, const float* __restrict__ dinv, u16* __restrict__ An){
  int j = threadIdx.x, i = blockIdx.x, b = blockIdx.y;
  float a = (float)pg[((long)b * 3 + 2) * 65536 + i * 256 + j] + (i == j ? 1.f : 0.f);
  An[((long)b * 256 + i) * 256 + j] = f2b(a * dinv[b * 256 + i] * dinv[b * 256 + j]);
}

// out[z][c][r] = in[z][r][c]; grid (R/32, C/32, Z); block (32,8)
__global__ void transpose_bf16(const u16* __restrict__ in, long sIn, int ldin,
                               u16* __restrict__ out, long sOut, int R){
  __shared__ u16 tile[32][33];
  const u16* ip = in + (long)blockIdx.z * sIn;
  u16* op = out + (long)blockIdx.z * sOut;
  int r0 = blockIdx.x * 32, c0 = blockIdx.y * 32;
  for (int yy = threadIdx.y; yy < 32; yy += 8)
    tile[yy][threadIdx.x] = ip[(long)(r0 + yy) * ldin + c0 + threadIdx.x];
  __syncthreads();
  for (int yy = threadIdx.y; yy < 32; yy += 8)
    op[(long)(c0 + yy) * R + r0 + threadIdx.x] = tile[threadIdx.x][yy];
}

// ---------------- host ----------------

extern "C" void kernel_launch(void* const* d_in, const int* in_sizes, int n_in,
                              void* d_out, int out_size, void* d_ws, size_t ws_size,
                              hipStream_t stream)
{
  const int* i1 = (const int*)d_in[0];
  const int* i2 = (const int*)d_in[1];
  const int* pg = (const int*)d_in[3];
  const float* e1 = (const float*)d_in[4];
  const float* e2 = (const float*)d_in[5];
  const float* wih[2][2]  = {{(const float*)d_in[6],  (const float*)d_in[10]},
                             {(const float*)d_in[14], (const float*)d_in[18]}};
  const float* whhI[2][2] = {{(const float*)d_in[7],  (const float*)d_in[11]},
                             {(const float*)d_in[15], (const float*)d_in[19]}};
  const float* bihI[2][2] = {{(const float*)d_in[8],  (const float*)d_in[12]},
                             {(const float*)d_in[16], (const float*)d_in[20]}};
  const float* bhhI[2][2] = {{(const float*)d_in[9],  (const float*)d_in[13]},
                             {(const float*)d_in[17], (const float*)d_in[21]}};
  const float* fc1w = (const float*)d_in[22]; const float* fc1b = (const float*)d_in[23];
  const float* fc2w = (const float*)d_in[24]; const float* fc2b = (const float*)d_in[25];
  const float* outw = (const float*)d_in[26]; const float* outb = (const float*)d_in[27];
  float* out = (float*)d_out;

  char* wp = (char*)d_ws;
  auto alloc = [&](size_t bytes) -> void* {
    void* r = (void*)wp; wp += (bytes + 255) & ~(size_t)255; return r;
  };
  const int dins[2] = {192, 1024};

  // ---- UNION region (192 MB): GRU phase = xg[2][SB][GATE]; GNN phase = An/nodeT/t1/nib/cat1
  char* ubase = wp;
  u16* xg = (u16*)alloc((size_t)2 * SB * GATE * 2);              // 201,326,592 B
  u16* An    = (u16*)(ubase);                                    // 16,777,216 B
  u16* nodeT = (u16*)(ubase + 16777216);                         // 33,554,432 B
  u16* t1    = (u16*)(ubase + 50331648);                         // 33,554,432 B
  u16* nib   = (u16*)(ubase + 83886080);                         // 33,554,432 B
  u16* cat1  = (u16*)(ubase + 117440512);                        // 67,108,864 B (ends 184,549,376 <= 192 MB)

  // ---- x1b / cat0 union (64 MB): x1 (layer-1 input, seq-major) then cat0 (node-major)
  u16* x1b  = (u16*)alloc((size_t)SB * 1024 * 2);
  u16* cat0 = x1b;

  u16* x0b   = (u16*)alloc((size_t)SB * 192 * 2);
  float* h   = (float*)alloc((size_t)2 * 2 * BATCH * HID * 4);   // [parity][dir][B*H]
  float* dinv= (float*)alloc((size_t)BATCH * S_LEN * 4);
  // NOTE: per-(layer) dir pairs must be ADJACENT (sizes are 256B multiples so alloc adds no pad)
  u16* wihp[2][2]; u16* whhp[2][2]; float* bihp[2][2]; float* bhhp[2][2];
  for (int l = 0; l < 2; l++)
    for (int d = 0; d < 2; d++) wihp[l][d] = (u16*)alloc((size_t)GATE * dins[l] * 2);
  for (int l = 0; l < 2; l++)
    for (int d = 0; d < 2; d++) whhp[l][d] = (u16*)alloc((size_t)GATE * HID * 2);
  for (int l = 0; l < 2; l++)
    for (int d = 0; d < 2; d++) bihp[l][d] = (float*)alloc((size_t)GATE * 4);
  for (int l = 0; l < 2; l++)
    for (int d = 0; d < 2; d++) bhhp[l][d] = (float*)alloc((size_t)GATE * 4);
  u16* fc1wb = (u16*)alloc((size_t)2 * HID * HID * 2);
  u16* fc2wb = (u16*)alloc((size_t)2 * HID * HID * 2);
  u16* outwb = (u16*)alloc((size_t)2 * HID * 1024 * 2);

  // workspace guard: if d_ws is too small, bail (clean absmax failure instead of HSA abort)
  size_t need = (size_t)(wp - (char*)d_ws);
  if (need > ws_size) return;

  // ---- weight prep ----
  for (int l = 0; l < 2; l++)
    for (int d = 0; d < 2; d++){
      permute_rows<<<256, 256, 0, stream>>>(wih[l][d], wihp[l][d], dins[l]);
      permute_rows<<<256, 256, 0, stream>>>(whhI[l][d], whhp[l][d], HID);
      permute_bias<<<6, 256, 0, stream>>>(bihI[l][d], bihp[l][d]);
      permute_bias<<<6, 256, 0, stream>>>(bhhI[l][d], bhhp[l][d]);
    }
  cvt_bf16<<<512, 256, 0, stream>>>(fc1w, fc1wb, (long)2 * HID * HID);
  cvt_bf16<<<512, 256, 0, stream>>>(fc2w, fc2wb, (long)2 * HID * HID);
  cvt_bf16<<<512, 256, 0, stream>>>(outw, outwb, (long)2 * HID * 1024);
  embed_kernel<<<SB, 192, 0, stream>>>(i1, i2, e1, e2, x0b);

  auto gemm = [&](const u16* A, int lda, long sAz, const u16* W, int ldw, long sWz,
                  const float* bias, u16* Cb, int ldc, long sCz, float* Cf,
                  int M, int N, int K, int Z, int flags){
    dim3 g(M / 128, N / 128, Z);
    gemm_bt<<<g, 256, 0, stream>>>(A, lda, sAz, W, ldw, sWz, bias, Cb, ldc, sCz, Cf, K, flags);
  };

  // ---- GRU layers ----
  for (int l = 0; l < 2; l++){
    const u16* xin = l ? x1b : x0b; int K = dins[l];
    for (int d = 0; d < 2; d++)
      gemm(xin, K, 0, wihp[l][d], K, 0, bihp[l][d],
           xg + (long)d * SB * GATE, GATE, 0, nullptr, SB, GATE, K, 1, 0);
    fill_zero<<<256, 256, 0, stream>>>(h, (long)2 * BATCH * HID);  // parity-0, both dirs
    for (int stp = 0; stp < 256; stp++){
      gru_step<<<dim3(32, 4, 2), 64, 0, stream>>>(
          whhp[l][0], bhhp[l][0], xg,
          h + (stp & 1) * 2 * BATCH * HID,
          h + ((stp + 1) & 1) * 2 * BATCH * HID,
          l == 0 ? x1b : nullptr, l == 0 ? nullptr : cat0, stp);
    }
    // final hidden lives in parity-0 after 256 steps
    copy_f32<<<256, 256, 0, stream>>>(h, out + (long)SB * HID + (long)l * 2 * BATCH * HID,
                                      (long)2 * BATCH * HID);
  }

  // ---- GNN ----  (xg is dead from here; An/nodeT/t1/nib/cat1 overlay its region)
  combine_cat<<<2048, 256, 0, stream>>>(cat0);     // node = yf + yb in cols 0:512
  deg_kernel<<<dim3(256, 128), 64, 0, stream>>>(pg, dinv);
  an_kernel<<<dim3(256, 128), 256, 0, stream>>>(pg, dinv, An);

  u16* cc = cat0; u16* cn = cat1;
  for (int hop = 0; hop < 2; hop++){
    // nodeT[b][h][s] = node[b][s][h] (node = cc[...,0:512], ld 1024)
    transpose_bf16<<<dim3(8, 16, 128), dim3(32, 8), 0, stream>>>(
        cc, (long)S_LEN * 1024, 1024, nodeT, (long)HID * S_LEN, S_LEN);
    // t1 = An @ node (batched)
    gemm(An, 256, (long)S_LEN * S_LEN, nodeT, 256, (long)HID * S_LEN, nullptr,
         t1, HID, (long)S_LEN * HID, nullptr, S_LEN, HID, S_LEN, BATCH, 0);
    // ni = relu(t1 @ fc1^T + b)
    gemm(t1, HID, 0, fc1wb + (long)hop * HID * HID, HID, 0, fc1b + hop * HID,
         nib, HID, 0, nullptr, SB, HID, HID, 1, 1);
    // t1 = An @ ni
    transpose_bf16<<<dim3(8, 16, 128), dim3(32, 8), 0, stream>>>(
        nib, (long)S_LEN * HID, HID, nodeT, (long)HID * S_LEN, S_LEN);
    gemm(An, 256, (long)S_LEN * S_LEN, nodeT, 256, (long)HID * S_LEN, nullptr,
         t1, HID, (long)S_LEN * HID, nullptr, S_LEN, HID, S_LEN, BATCH, 0);
    // ni2 = relu(t1 @ fc2^T + b) -> cc[...,512:1024]
    gemm(t1, HID, 0, fc2wb + (long)hop * HID * HID, HID, 0, fc2b + hop * HID,
         cc + HID, 1024, 0, nullptr, SB, HID, HID, 1, 1);
    // node' = relu(cat @ out_w^T + b); last hop writes only d_out f32 (s,b layout)
    gemm(cc, 1024, 0, outwb + (long)hop * HID * 1024, 1024, 0, outb + hop * HID,
         (hop == 1) ? nullptr : cn, 1024, 0, (hop == 1) ? out : nullptr, SB, HID, 1024, 1, 1);
    u16* tmp = cc; cc = cn; cn = tmp;
  }
}

// Round 4
// 8678.336 us; speedup vs baseline: 1.2752x; 1.2752x over previous
//
#include <hip/hip_runtime.h>
#include <hip/hip_bf16.h>

using short8 = __attribute__((ext_vector_type(8))) short;
using f32x4  = __attribute__((ext_vector_type(4))) float;
typedef unsigned short u16;
typedef unsigned int u32;

#define S_LEN 256
#define BATCH 128
#define HID   512
#define GATE  1536
#define SB    32768   // S_LEN*BATCH

static __device__ __forceinline__ u16 f2b(float f){
  union { float f; u32 u; } v; v.f = f;
  u32 r = v.u + 0x7fffu + ((v.u >> 16) & 1u);
  return (u16)(r >> 16);
}
static __device__ __forceinline__ float b2f(u16 h){
  union { u32 u; float f; } v; v.u = ((u32)h) << 16; return v.f;
}
static __device__ __forceinline__ f32x4 mfma16(short8 a, short8 b, f32x4 c){
  return __builtin_amdgcn_mfma_f32_16x16x32_bf16(a, b, c, 0, 0, 0);
}

// ---------------- utility kernels ----------------

__global__ void fill_zero(float* p, long n){
  long i = (long)blockIdx.x * blockDim.x + threadIdx.x;
  long st = (long)gridDim.x * blockDim.x;
  for (; i < n; i += st) p[i] = 0.f;
}

__global__ void cvt_bf16(const float* in, u16* out, long n){
  long i = (long)blockIdx.x * blockDim.x + threadIdx.x;
  long st = (long)gridDim.x * blockDim.x;
  for (; i < n; i += st) out[i] = f2b(in[i]);
}

// gate-row permutation: old row = g*512 + c  ->  new row = 48*(c>>4) + 16*g + (c&15)
__global__ void permute_rows(const float* in, u16* out, int K){
  long n = (long)GATE * K;
  long i = (long)blockIdx.x * blockDim.x + threadIdx.x;
  long st = (long)gridDim.x * blockDim.x;
  for (; i < n; i += st){
    int orow = (int)(i / K); int k = (int)(i - (long)orow * K);
    int g = orow >> 9, c = orow & 511;
    int nrow = ((c >> 4) * 48) + (g << 4) + (c & 15);
    out[(long)nrow * K + k] = f2b(in[i]);
  }
}

__global__ void permute_bias(const float* in, float* out){
  int orow = blockIdx.x * blockDim.x + threadIdx.x;
  if (orow < GATE){
    int g = orow >> 9, c = orow & 511;
    out[((c >> 4) * 48) + (g << 4) + (c & 15)] = in[orow];
  }
}

// x0[s*B+b][0:128]=emb1[i1], [128:192]=emb2[i2] (0 if idx==0), bf16
__global__ void embed_kernel(const int* __restrict__ i1, const int* __restrict__ i2,
                             const float* __restrict__ e1, const float* __restrict__ e2,
                             u16* __restrict__ x0){
  int row = blockIdx.x; int t = threadIdx.x;
  float v;
  if (t < 128) v = e1[(long)i1[row] * 128 + t];
  else { int ix = i2[row]; v = ix ? e2[(long)ix * 64 + (t - 128)] : 0.f; }
  x0[(long)row * 192 + t] = f2b(v);
}

// ---------------- generic bf16 MFMA GEMM: C = A[M,K] * W[N,K]^T (+bias)(+relu) ----------------
__global__ __launch_bounds__(256) void gemm_bt(
    const u16* __restrict__ A, int lda, long sAz,
    const u16* __restrict__ W, int ldw, long sWz,
    const float* __restrict__ bias,
    u16* __restrict__ Cb, int ldc, long sCz,
    float* __restrict__ Cf,       // optional f32 out, (b,s)->(s,b) transposed, ld 512
    int K, int flags)             // bit0 = relu
{
  __shared__ u16 As[128 * 40];
  __shared__ u16 Ws[128 * 40];
  const int tid = threadIdx.x;
  const int m0 = blockIdx.x * 128, n0 = blockIdx.y * 128;
  const long z = blockIdx.z;
  const u16* Ab = A + z * sAz;
  const u16* Wb = W + z * sWz;
  const int r0 = tid >> 2, kg = (tid & 3) * 8;
  const int lane = tid & 63, w = tid >> 6;
  const int wr = w >> 1, wc = w & 1;
  const int col = lane & 15, q = lane >> 4;
  f32x4 acc[4][4];
#pragma unroll
  for (int i = 0; i < 4; i++)
#pragma unroll
    for (int j = 0; j < 4; j++) acc[i][j] = (f32x4){0.f, 0.f, 0.f, 0.f};

  for (int k0 = 0; k0 < K; k0 += 32){
    uint4 a0 = *(const uint4*)(Ab + (long)(m0 + r0) * lda + k0 + kg);
    uint4 a1 = *(const uint4*)(Ab + (long)(m0 + r0 + 64) * lda + k0 + kg);
    uint4 w0 = *(const uint4*)(Wb + (long)(n0 + r0) * ldw + k0 + kg);
    uint4 w1 = *(const uint4*)(Wb + (long)(n0 + r0 + 64) * ldw + k0 + kg);
    __syncthreads();
    *(uint4*)(As + r0 * 40 + kg) = a0;
    *(uint4*)(As + (r0 + 64) * 40 + kg) = a1;
    *(uint4*)(Ws + r0 * 40 + kg) = w0;
    *(uint4*)(Ws + (r0 + 64) * 40 + kg) = w1;
    __syncthreads();
    short8 af[4], bf[4];
#pragma unroll
    for (int i = 0; i < 4; i++) af[i] = *(const short8*)(As + (wr * 64 + i * 16 + col) * 40 + q * 8);
#pragma unroll
    for (int j = 0; j < 4; j++) bf[j] = *(const short8*)(Ws + (wc * 64 + j * 16 + col) * 40 + q * 8);
#pragma unroll
    for (int i = 0; i < 4; i++)
#pragma unroll
      for (int j = 0; j < 4; j++)
        acc[i][j] = mfma16(af[i], bf[j], acc[i][j]);
  }

#pragma unroll
  for (int i = 0; i < 4; i++)
#pragma unroll
    for (int j = 0; j < 4; j++){
      int n = n0 + wc * 64 + j * 16 + col;
      float bv = bias ? bias[n] : 0.f;
#pragma unroll
      for (int r = 0; r < 4; r++){
        int m = m0 + wr * 64 + i * 16 + q * 4 + r;
        float v = acc[i][j][r] + bv;
        if (flags & 1) v = fmaxf(v, 0.f);
        if (Cb) Cb[z * sCz + (long)m * ldc + n] = f2b(v);
        if (Cf){ int s = m & 255, b = m >> 8; Cf[((long)s * 128 + b) * 512 + n] = v; }
      }
    }
}

// ---------------- persistent GRU layer (cooperative launch) ----------------
// grid 256 x 64: blockIdx.x -> dir = b>>7; r=b&127: cb=r>>2 (32 ch-blocks), bt=r&3 (batch tile of 32)
// Sync groups: (dir,bt) = 8 groups of 32 blocks; monotonic atomic-counter barrier per group.
// W_hh slice LDS-resident; f32 carry in registers; h exchanged as bf16 (parity dbuf).
__global__ __launch_bounds__(64) void gru_persist(
    const u16* __restrict__ whh,    // [2][GATE*HID] permuted bf16 (dirs adjacent)
    const float* __restrict__ bhh,  // [2][GATE] permuted
    const u16* __restrict__ xg,     // [2][SB*GATE] bf16 (permuted cols)
    u16* __restrict__ hbf,          // [2 parity][2 dir][BATCH*HID] bf16, parity0 zeroed
    u16* __restrict__ y_cat,        // layer0: x1 [SB,1024] seq-major, else null
    u16* __restrict__ y_node,       // layer1: cat0 [b][s][dir*512+c], else null
    float* __restrict__ hT,         // final hidden out [2 dir][BATCH*HID] f32
    u32* __restrict__ ctr)          // [8*64] u32, zeroed; group g uses ctr[g*64]
{
  const int bid = blockIdx.x;
  const int dir = bid >> 7, rr_ = bid & 127;
  const int cb = rr_ >> 2, bt = rr_ & 3, b0 = bt * 32;
  const int lane = threadIdx.x, col = lane & 15, q = lane >> 4;
  u32* myc = ctr + (dir * 4 + bt) * 64;

  __shared__ u16 Ws[48 * 520];
  {
    const u16* Wd = whh + (long)dir * GATE * HID + (long)(48 * cb) * HID;
    for (int i = lane; i < 48 * 64; i += 64){
      int row = i >> 6, k8 = (i & 63) << 3;
      *(short8*)(Ws + row * 520 + k8) = *(const short8*)(Wd + (long)row * HID + k8);
    }
  }
  __syncthreads();

  const u16* xgd = xg + (long)dir * SB * GATE + 48 * cb;
  const float* bh = bhh + dir * GATE + 48 * cb;
  const float bhr = bh[col], bhz = bh[16 + col], bhn = bh[32 + col];
  const int c = cb * 16 + col;

  float hold[2][4];
#pragma unroll
  for (int ii = 0; ii < 2; ii++)
#pragma unroll
    for (int r = 0; r < 4; r++) hold[ii][r] = 0.f;

  for (int s = 0; s < 256; s++){
    const int t = dir ? (255 - s) : s;
    // prefetch xg slice for this step (independent of the barrier)
    u16 xv[2][4][3];
#pragma unroll
    for (int ii = 0; ii < 2; ii++)
#pragma unroll
      for (int r = 0; r < 4; r++){
        const u16* xp = xgd + ((long)t * BATCH + (b0 + ii * 16 + q * 4 + r)) * GATE;
#pragma unroll
        for (int g = 0; g < 3; g++) xv[ii][r][g] = xp[16 * g + col];
      }
    if (s){
      const u32 tgt = (u32)(32 * s);
      if (lane == 0)
        while (__hip_atomic_load(myc, __ATOMIC_RELAXED, __HIP_MEMORY_SCOPE_AGENT) < tgt)
          __builtin_amdgcn_s_sleep(1);
      __syncthreads();          // broadcast barrier-done to all lanes
      __threadfence();          // acquire: see other blocks' h writes
    }
    const u16* hin = hbf + ((long)((s & 1) * 2 + dir)) * (BATCH * HID);
    u16* hout = hbf + ((long)(((s & 1) ^ 1) * 2 + dir)) * (BATCH * HID);

    f32x4 acc[2][3];
#pragma unroll
    for (int ii = 0; ii < 2; ii++)
#pragma unroll
      for (int g = 0; g < 3; g++) acc[ii][g] = (f32x4){0.f, 0.f, 0.f, 0.f};

    for (int kk = 0; kk < HID; kk += 32){
      short8 af[2];
#pragma unroll
      for (int ii = 0; ii < 2; ii++)
        af[ii] = *(const short8*)(hin + (long)(b0 + ii * 16 + col) * HID + kk + q * 8);
#pragma unroll
      for (int g = 0; g < 3; g++){
        short8 bfr = *(const short8*)(Ws + (16 * g + col) * 520 + kk + q * 8);
        acc[0][g] = mfma16(af[0], bfr, acc[0][g]);
        acc[1][g] = mfma16(af[1], bfr, acc[1][g]);
      }
    }

#pragma unroll
    for (int ii = 0; ii < 2; ii++)
#pragma unroll
      for (int r = 0; r < 4; r++){
        int b = b0 + ii * 16 + q * 4 + r;
        float xr = b2f(xv[ii][r][0]);
        float xz = b2f(xv[ii][r][1]);
        float xn = b2f(xv[ii][r][2]);
        float gr = 1.f / (1.f + expf(-(xr + acc[ii][0][r] + bhr)));
        float gz = 1.f / (1.f + expf(-(xz + acc[ii][1][r] + bhz)));
        float gn = tanhf(xn + gr * (acc[ii][2][r] + bhn));
        float hnew = (1.f - gz) * gn + gz * hold[ii][r];
        hold[ii][r] = hnew;
        u16 hb = f2b(hnew);
        hout[(long)b * HID + c] = hb;
        if (y_cat)  y_cat[((long)t * BATCH + b) * 1024 + dir * HID + c] = hb;
        if (y_node) y_node[((long)b * 256 + t) * 1024 + dir * HID + c] = hb;
      }
    __threadfence();            // release: h writes visible before counter bump
    if (lane == 0) __hip_atomic_fetch_add(myc, 1u, __ATOMIC_RELAXED, __HIP_MEMORY_SCOPE_AGENT);
  }

#pragma unroll
  for (int ii = 0; ii < 2; ii++)
#pragma unroll
    for (int r = 0; r < 4; r++){
      int b = b0 + ii * 16 + q * 4 + r;
      hT[(long)dir * BATCH * HID + (long)b * HID + c] = hold[ii][r];
    }
}

// cat[row][c] += cat[row][512+c] (both bf16), node = yf + yb
__global__ void combine_cat(u16* __restrict__ cat){
  long n = (long)SB * HID;
  long i = (long)blockIdx.x * blockDim.x + threadIdx.x;
  long st = (long)gridDim.x * blockDim.x;
  for (; i < n; i += st){
    long row = i >> 9; int c = (int)(i & 511);
    u16* p = cat + row * 1024;
    p[c] = f2b(b2f(p[c]) + b2f(p[512 + c]));
  }
}

// ---------------- GNN prep ----------------

__global__ __launch_bounds__(64) void deg_kernel(const int* __restrict__ pg, float* __restrict__ dinv){
  int i = blockIdx.x, b = blockIdx.y, lane = threadIdx.x;
  const int* p = pg + ((long)b * 3 + 2) * 65536 + i * 256 + lane * 4;
  int4 v = *(const int4*)p;
  int s = v.x + v.y + v.z + v.w;
  for (int o = 32; o; o >>= 1) s += __shfl_down(s, o);
  if (lane == 0) dinv[b * 256 + i] = 1.f / sqrtf((float)(s + 1));
}

__global__ void an_kernel(const int* __restrict__ pg, const float* __restrict__ dinv, u16* __restrict__ An){
  int j = threadIdx.x, i = blockIdx.x, b = blockIdx.y;
  float a = (float)pg[((long)b * 3 + 2) * 65536 + i * 256 + j] + (i == j ? 1.f : 0.f);
  An[((long)b * 256 + i) * 256 + j] = f2b(a * dinv[b * 256 + i] * dinv[b * 256 + j]);
}

// out[z][c][r] = in[z][r][c]; grid (R/32, C/32, Z); block (32,8)
__global__ void transpose_bf16(const u16* __restrict__ in, long sIn, int ldin,
                               u16* __restrict__ out, long sOut, int R){
  __shared__ u16 tile[32][33];
  const u16* ip = in + (long)blockIdx.z * sIn;
  u16* op = out + (long)blockIdx.z * sOut;
  int r0 = blockIdx.x * 32, c0 = blockIdx.y * 32;
  for (int yy = threadIdx.y; yy < 32; yy += 8)
    tile[yy][threadIdx.x] = ip[(long)(r0 + yy) * ldin + c0 + threadIdx.x];
  __syncthreads();
  for (int yy = threadIdx.y; yy < 32; yy += 8)
    op[(long)(c0 + yy) * R + r0 + threadIdx.x] = tile[threadIdx.x][yy];
}

// ---------------- host ----------------

extern "C" void kernel_launch(void* const* d_in, const int* in_sizes, int n_in,
                              void* d_out, int out_size, void* d_ws, size_t ws_size,
                              hipStream_t stream)
{
  const int* i1 = (const int*)d_in[0];
  const int* i2 = (const int*)d_in[1];
  const int* pg = (const int*)d_in[3];
  const float* e1 = (const float*)d_in[4];
  const float* e2 = (const float*)d_in[5];
  const float* wih[2][2]  = {{(const float*)d_in[6],  (const float*)d_in[10]},
                             {(const float*)d_in[14], (const float*)d_in[18]}};
  const float* whhI[2][2] = {{(const float*)d_in[7],  (const float*)d_in[11]},
                             {(const float*)d_in[15], (const float*)d_in[19]}};
  const float* bihI[2][2] = {{(const float*)d_in[8],  (const float*)d_in[12]},
                             {(const float*)d_in[16], (const float*)d_in[20]}};
  const float* bhhI[2][2] = {{(const float*)d_in[9],  (const float*)d_in[13]},
                             {(const float*)d_in[17], (const float*)d_in[21]}};
  const float* fc1w = (const float*)d_in[22]; const float* fc1b = (const float*)d_in[23];
  const float* fc2w = (const float*)d_in[24]; const float* fc2b = (const float*)d_in[25];
  const float* outw = (const float*)d_in[26]; const float* outb = (const float*)d_in[27];
  float* out = (float*)d_out;

  char* wp = (char*)d_ws;
  auto alloc = [&](size_t bytes) -> void* {
    void* r = (void*)wp; wp += (bytes + 255) & ~(size_t)255; return r;
  };
  const int dins[2] = {192, 1024};

  // ---- UNION region (192 MB): GRU phase = xg[2][SB][GATE]; GNN phase = An/nodeT/t1/nib/cat1
  char* ubase = wp;
  u16* xg = (u16*)alloc((size_t)2 * SB * GATE * 2);              // 201,326,592 B
  u16* An    = (u16*)(ubase);                                    // 16,777,216 B
  u16* nodeT = (u16*)(ubase + 16777216);                         // 33,554,432 B
  u16* t1    = (u16*)(ubase + 50331648);                         // 33,554,432 B
  u16* nib   = (u16*)(ubase + 83886080);                         // 33,554,432 B
  u16* cat1  = (u16*)(ubase + 117440512);                        // 67,108,864 B

  // ---- x1b / cat0 union (64 MB)
  u16* x1b  = (u16*)alloc((size_t)SB * 1024 * 2);
  u16* cat0 = x1b;

  u16* x0b   = (u16*)alloc((size_t)SB * 192 * 2);
  u16* hbf   = (u16*)alloc((size_t)2 * 2 * BATCH * HID * 2);     // [parity][dir][B*H] bf16
  u32* ctr   = (u32*)alloc((size_t)8 * 64 * 4);                  // 8 barrier groups, 256B apart
  float* dinv= (float*)alloc((size_t)BATCH * S_LEN * 4);
  u16* wihp[2][2]; u16* whhp[2][2]; float* bihp[2][2]; float* bhhp[2][2];
  for (int l = 0; l < 2; l++)
    for (int d = 0; d < 2; d++) wihp[l][d] = (u16*)alloc((size_t)GATE * dins[l] * 2);
  for (int l = 0; l < 2; l++)
    for (int d = 0; d < 2; d++) whhp[l][d] = (u16*)alloc((size_t)GATE * HID * 2);
  for (int l = 0; l < 2; l++)
    for (int d = 0; d < 2; d++) bihp[l][d] = (float*)alloc((size_t)GATE * 4);
  for (int l = 0; l < 2; l++)
    for (int d = 0; d < 2; d++) bhhp[l][d] = (float*)alloc((size_t)GATE * 4);
  u16* fc1wb = (u16*)alloc((size_t)2 * HID * HID * 2);
  u16* fc2wb = (u16*)alloc((size_t)2 * HID * HID * 2);
  u16* outwb = (u16*)alloc((size_t)2 * HID * 1024 * 2);

  size_t need = (size_t)(wp - (char*)d_ws);
  if (need > ws_size) return;   // clean failure instead of HSA abort

  // ---- weight prep ----
  for (int l = 0; l < 2; l++)
    for (int d = 0; d < 2; d++){
      permute_rows<<<256, 256, 0, stream>>>(wih[l][d], wihp[l][d], dins[l]);
      permute_rows<<<256, 256, 0, stream>>>(whhI[l][d], whhp[l][d], HID);
      permute_bias<<<6, 256, 0, stream>>>(bihI[l][d], bihp[l][d]);
      permute_bias<<<6, 256, 0, stream>>>(bhhI[l][d], bhhp[l][d]);
    }
  cvt_bf16<<<512, 256, 0, stream>>>(fc1w, fc1wb, (long)2 * HID * HID);
  cvt_bf16<<<512, 256, 0, stream>>>(fc2w, fc2wb, (long)2 * HID * HID);
  cvt_bf16<<<512, 256, 0, stream>>>(outw, outwb, (long)2 * HID * 1024);
  embed_kernel<<<SB, 192, 0, stream>>>(i1, i2, e1, e2, x0b);

  auto gemm = [&](const u16* A, int lda, long sAz, const u16* W, int ldw, long sWz,
                  const float* bias, u16* Cb, int ldc, long sCz, float* Cf,
                  int M, int N, int K, int Z, int flags){
    dim3 g(M / 128, N / 128, Z);
    gemm_bt<<<g, 256, 0, stream>>>(A, lda, sAz, W, ldw, sWz, bias, Cb, ldc, sCz, Cf, K, flags);
  };

  // ---- GRU layers (persistent cooperative kernel per layer) ----
  for (int l = 0; l < 2; l++){
    const u16* xin = l ? x1b : x0b; int K = dins[l];
    for (int d = 0; d < 2; d++)
      gemm(xin, K, 0, wihp[l][d], K, 0, bihp[l][d],
           xg + (long)d * SB * GATE, GATE, 0, nullptr, SB, GATE, K, 1, 0);
    // zero parity buffers (h=0 start) + barrier counters
    fill_zero<<<128, 256, 0, stream>>>((float*)hbf, (long)(2 * 2 * BATCH * HID) / 2);
    fill_zero<<<1, 256, 0, stream>>>((float*)ctr, 512);
    const u16* whh_l = whhp[l][0];
    const float* bhh_l = bhhp[l][0];
    u16* ycat = (l == 0) ? x1b : nullptr;
    u16* ynode = (l == 0) ? nullptr : cat0;
    float* hT = out + (long)SB * HID + (long)l * 2 * BATCH * HID;
    void* args[8] = { (void*)&whh_l, (void*)&bhh_l, (void*)&xg, (void*)&hbf,
                      (void*)&ycat, (void*)&ynode, (void*)&hT, (void*)&ctr };
    hipError_t e = hipLaunchCooperativeKernel((const void*)gru_persist, dim3(256), dim3(64),
                                              args, 0, stream);
    (void)e;
  }

  // ---- GNN ----  (xg dead; An/nodeT/t1/nib/cat1 overlay its region)
  combine_cat<<<2048, 256, 0, stream>>>(cat0);
  deg_kernel<<<dim3(256, 128), 64, 0, stream>>>(pg, dinv);
  an_kernel<<<dim3(256, 128), 256, 0, stream>>>(pg, dinv, An);

  u16* cc = cat0; u16* cn = cat1;
  for (int hop = 0; hop < 2; hop++){
    transpose_bf16<<<dim3(8, 16, 128), dim3(32, 8), 0, stream>>>(
        cc, (long)S_LEN * 1024, 1024, nodeT, (long)HID * S_LEN, S_LEN);
    gemm(An, 256, (long)S_LEN * S_LEN, nodeT, 256, (long)HID * S_LEN, nullptr,
         t1, HID, (long)S_LEN * HID, nullptr, S_LEN, HID, S_LEN, BATCH, 0);
    gemm(t1, HID, 0, fc1wb + (long)hop * HID * HID, HID, 0, fc1b + hop * HID,
         nib, HID, 0, nullptr, SB, HID, HID, 1, 1);
    transpose_bf16<<<dim3(8, 16, 128), dim3(32, 8), 0, stream>>>(
        nib, (long)S_LEN * HID, HID, nodeT, (long)HID * S_LEN, S_LEN);
    gemm(An, 256, (long)S_LEN * S_LEN, nodeT, 256, (long)HID * S_LEN, nullptr,
         t1, HID, (long)S_LEN * HID, nullptr, S_LEN, HID, S_LEN, BATCH, 0);
    gemm(t1, HID, 0, fc2wb + (long)hop * HID * HID, HID, 0, fc2b + hop * HID,
         cc + HID, 1024, 0, nullptr, SB, HID, HID, 1, 1);
    gemm(cc, 1024, 0, outwb + (long)hop * HID * 1024, 1024, 0, outb + hop * HID,
         (hop == 1) ? nullptr : cn, 1024, 0, (hop == 1) ? out : nullptr, SB, HID, 1024, 1, 1);
    u16* tmp = cc; cc = cn; cn = tmp;
  }
}

// Round 5
// 5597.022 us; speedup vs baseline: 1.9772x; 1.5505x over previous
//
#include <hip/hip_runtime.h>
#include <hip/hip_bf16.h>

using short8 = __attribute__((ext_vector_type(8))) short;
using f32x4  = __attribute__((ext_vector_type(4))) float;
typedef unsigned short u16;
typedef unsigned int u32;

#define S_LEN 256
#define BATCH 128
#define HID   512
#define GATE  1536
#define SB    32768   // S_LEN*BATCH

static __device__ __forceinline__ u16 f2b(float f){
  union { float f; u32 u; } v; v.f = f;
  u32 r = v.u + 0x7fffu + ((v.u >> 16) & 1u);
  return (u16)(r >> 16);
}
static __device__ __forceinline__ float b2f(u16 h){
  union { u32 u; float f; } v; v.u = ((u32)h) << 16; return v.f;
}
static __device__ __forceinline__ f32x4 mfma16(short8 a, short8 b, f32x4 c){
  return __builtin_amdgcn_mfma_f32_16x16x32_bf16(a, b, c, 0, 0, 0);
}

// ---------------- utility kernels ----------------

__global__ void fill_zero(float* p, long n){
  long i = (long)blockIdx.x * blockDim.x + threadIdx.x;
  long st = (long)gridDim.x * blockDim.x;
  for (; i < n; i += st) p[i] = 0.f;
}

__global__ void cvt_bf16(const float* in, u16* out, long n){
  long i = (long)blockIdx.x * blockDim.x + threadIdx.x;
  long st = (long)gridDim.x * blockDim.x;
  for (; i < n; i += st) out[i] = f2b(in[i]);
}

// gate-row permutation: old row = g*512 + c  ->  new row = 48*(c>>4) + 16*g + (c&15)
__global__ void permute_rows(const float* in, u16* out, int K){
  long n = (long)GATE * K;
  long i = (long)blockIdx.x * blockDim.x + threadIdx.x;
  long st = (long)gridDim.x * blockDim.x;
  for (; i < n; i += st){
    int orow = (int)(i / K); int k = (int)(i - (long)orow * K);
    int g = orow >> 9, c = orow & 511;
    int nrow = ((c >> 4) * 48) + (g << 4) + (c & 15);
    out[(long)nrow * K + k] = f2b(in[i]);
  }
}

__global__ void permute_bias(const float* in, float* out){
  int orow = blockIdx.x * blockDim.x + threadIdx.x;
  if (orow < GATE){
    int g = orow >> 9, c = orow & 511;
    out[((c >> 4) * 48) + (g << 4) + (c & 15)] = in[orow];
  }
}

// x0[s*B+b][0:128]=emb1[i1], [128:192]=emb2[i2] (0 if idx==0), bf16
__global__ void embed_kernel(const int* __restrict__ i1, const int* __restrict__ i2,
                             const float* __restrict__ e1, const float* __restrict__ e2,
                             u16* __restrict__ x0){
  int row = blockIdx.x; int t = threadIdx.x;
  float v;
  if (t < 128) v = e1[(long)i1[row] * 128 + t];
  else { int ix = i2[row]; v = ix ? e2[(long)ix * 64 + (t - 128)] : 0.f; }
  x0[(long)row * 192 + t] = f2b(v);
}

// ---------------- generic bf16 MFMA GEMM: C = A[M,K] * W[N,K]^T (+bias)(+relu) ----------------
__global__ __launch_bounds__(256) void gemm_bt(
    const u16* __restrict__ A, int lda, long sAz,
    const u16* __restrict__ W, int ldw, long sWz,
    const float* __restrict__ bias,
    u16* __restrict__ Cb, int ldc, long sCz,
    float* __restrict__ Cf,       // optional f32 out, (b,s)->(s,b) transposed, ld 512
    int K, int flags)             // bit0 = relu
{
  __shared__ u16 As[128 * 40];
  __shared__ u16 Ws[128 * 40];
  const int tid = threadIdx.x;
  const int m0 = blockIdx.x * 128, n0 = blockIdx.y * 128;
  const long z = blockIdx.z;
  const u16* Ab = A + z * sAz;
  const u16* Wb = W + z * sWz;
  const int r0 = tid >> 2, kg = (tid & 3) * 8;
  const int lane = tid & 63, w = tid >> 6;
  const int wr = w >> 1, wc = w & 1;
  const int col = lane & 15, q = lane >> 4;
  f32x4 acc[4][4];
#pragma unroll
  for (int i = 0; i < 4; i++)
#pragma unroll
    for (int j = 0; j < 4; j++) acc[i][j] = (f32x4){0.f, 0.f, 0.f, 0.f};

  for (int k0 = 0; k0 < K; k0 += 32){
    uint4 a0 = *(const uint4*)(Ab + (long)(m0 + r0) * lda + k0 + kg);
    uint4 a1 = *(const uint4*)(Ab + (long)(m0 + r0 + 64) * lda + k0 + kg);
    uint4 w0 = *(const uint4*)(Wb + (long)(n0 + r0) * ldw + k0 + kg);
    uint4 w1 = *(const uint4*)(Wb + (long)(n0 + r0 + 64) * ldw + k0 + kg);
    __syncthreads();
    *(uint4*)(As + r0 * 40 + kg) = a0;
    *(uint4*)(As + (r0 + 64) * 40 + kg) = a1;
    *(uint4*)(Ws + r0 * 40 + kg) = w0;
    *(uint4*)(Ws + (r0 + 64) * 40 + kg) = w1;
    __syncthreads();
    short8 af[4], bf[4];
#pragma unroll
    for (int i = 0; i < 4; i++) af[i] = *(const short8*)(As + (wr * 64 + i * 16 + col) * 40 + q * 8);
#pragma unroll
    for (int j = 0; j < 4; j++) bf[j] = *(const short8*)(Ws + (wc * 64 + j * 16 + col) * 40 + q * 8);
#pragma unroll
    for (int i = 0; i < 4; i++)
#pragma unroll
      for (int j = 0; j < 4; j++)
        acc[i][j] = mfma16(af[i], bf[j], acc[i][j]);
  }

#pragma unroll
  for (int i = 0; i < 4; i++)
#pragma unroll
    for (int j = 0; j < 4; j++){
      int n = n0 + wc * 64 + j * 16 + col;
      float bv = bias ? bias[n] : 0.f;
#pragma unroll
      for (int r = 0; r < 4; r++){
        int m = m0 + wr * 64 + i * 16 + q * 4 + r;
        float v = acc[i][j][r] + bv;
        if (flags & 1) v = fmaxf(v, 0.f);
        if (Cb) Cb[z * sCz + (long)m * ldc + n] = f2b(v);
        if (Cf){ int s = m & 255, b = m >> 8; Cf[((long)s * 128 + b) * 512 + n] = v; }
      }
    }
}

// ---------------- persistent GRU layer (cooperative launch) ----------------
// grid 256 x 64: dir = bid>>7; r=bid&127: cb = r>>3 (16 blocks of 32 channels),
// bt = r&7 (8 tiles of 16 batches). Sync group = (dir,bt): 16 groups x 16 slots.
// No cache-maintenance fences: h exchange via device-coherent atomics (IF-homed);
// barrier = per-block monotone flag (1 uncontended RMW) + wide poll (1 round trip).
__global__ __launch_bounds__(64) void gru_persist(
    const u16* __restrict__ whh,    // [2][GATE*HID] permuted bf16 (dirs adjacent)
    const float* __restrict__ bhh,  // [2][GATE] permuted
    const u16* __restrict__ xg,     // [2][SB*GATE] bf16 (permuted cols)
    u16* __restrict__ hbf,          // [2 parity][2 dir][BATCH*HID] bf16, parity0 zeroed
    u16* __restrict__ y_cat,        // layer0: x1 [SB,1024] seq-major, else null
    u16* __restrict__ y_node,       // layer1: cat0 [b][s][dir*512+c], else null
    float* __restrict__ hT,         // final hidden out [2 dir][BATCH*HID] f32
    u32* __restrict__ flags)        // [16 groups][16 slots] u32, zeroed
{
  const int bid = blockIdx.x;
  const int dir = bid >> 7, r7 = bid & 127;
  const int cb = r7 >> 3, bt = r7 & 7, b0 = bt * 16;
  const int lane = threadIdx.x, col = lane & 15, q = lane >> 4;
  u32* gflag = flags + (dir * 8 + bt) * 16;
  u32* myflag = gflag + cb;

  __shared__ u16 Ws[96 * 520];   // 96 rows (2 col-groups x 3 gates x 16), pad-520
  {
    const u16* Wd = whh + (long)dir * GATE * HID + (long)(96 * cb) * HID;
    for (int i = lane; i < 96 * 64; i += 64){
      int row = i >> 6, k8 = (i & 63) << 3;
      *(short8*)(Ws + row * 520 + k8) = *(const short8*)(Wd + (long)row * HID + k8);
    }
  }
  __syncthreads();

  const u16* xgd = xg + (long)dir * SB * GATE;
  const float* bh = bhh + dir * GATE;
  float bhv[2][3];
#pragma unroll
  for (int cg = 0; cg < 2; cg++)
#pragma unroll
    for (int g = 0; g < 3; g++)
      bhv[cg][g] = bh[48 * (2 * cb + cg) + 16 * g + col];

  float hold[2][4];
#pragma unroll
  for (int cg = 0; cg < 2; cg++)
#pragma unroll
    for (int r = 0; r < 4; r++) hold[cg][r] = 0.f;

  for (int s = 0; s < 256; s++){
    const int t = dir ? (255 - s) : s;
    // prefetch xg slice for this step (issued before the spin)
    u16 xv[2][4][3];
#pragma unroll
    for (int cg = 0; cg < 2; cg++)
#pragma unroll
      for (int r = 0; r < 4; r++){
        const u16* xp = xgd + ((long)t * BATCH + (b0 + q * 4 + r)) * GATE + 48 * (2 * cb + cg);
#pragma unroll
        for (int g = 0; g < 3; g++) xv[cg][r][g] = xp[16 * g + col];
      }
    if (s){
      const u32 tgt = (u32)s;
      for (;;){
        u32 v = __hip_atomic_load(gflag + (lane & 15), __ATOMIC_RELAXED, __HIP_MEMORY_SCOPE_AGENT);
        if (__ballot(v >= tgt) == ~0ull) break;
        __builtin_amdgcn_s_sleep(1);
      }
    }
    const u16* hin = hbf + ((long)((s & 1) * 2 + dir)) * (BATCH * HID);
    u16* hout = hbf + ((long)(((s & 1) ^ 1) * 2 + dir)) * (BATCH * HID);

    f32x4 acc[6];
#pragma unroll
    for (int tl = 0; tl < 6; tl++) acc[tl] = (f32x4){0.f, 0.f, 0.f, 0.f};

    for (int kk = 0; kk < HID; kk += 32){
      // coherent read of h rows b0+col, k = kk+q*8..+7 (4 dwords)
      u32* hp = (u32*)(hin + (long)(b0 + col) * HID + kk + q * 8);
      union { short8 s8; u32 u[4]; } a;
#pragma unroll
      for (int j = 0; j < 4; j++)
        a.u[j] = __hip_atomic_load(hp + j, __ATOMIC_RELAXED, __HIP_MEMORY_SCOPE_AGENT);
#pragma unroll
      for (int tl = 0; tl < 6; tl++){
        short8 bfr = *(const short8*)(Ws + (tl * 16 + col) * 520 + kk + q * 8);
        acc[tl] = mfma16(a.s8, bfr, acc[tl]);
      }
    }

#pragma unroll
    for (int cg = 0; cg < 2; cg++)
#pragma unroll
      for (int r = 0; r < 4; r++){
        int b = b0 + q * 4 + r;
        int c = cb * 32 + cg * 16 + col;
        float xr = b2f(xv[cg][r][0]);
        float xz = b2f(xv[cg][r][1]);
        float xn = b2f(xv[cg][r][2]);
        float gr = 1.f / (1.f + expf(-(xr + acc[cg * 3 + 0][r] + bhv[cg][0])));
        float gz = 1.f / (1.f + expf(-(xz + acc[cg * 3 + 1][r] + bhv[cg][1])));
        float gn = tanhf(xn + gr * (acc[cg * 3 + 2][r] + bhv[cg][2]));
        float hnew = (1.f - gz) * gn + gz * hold[cg][r];
        hold[cg][r] = hnew;
        u16 hb = f2b(hnew);
        if (y_cat)  y_cat[((long)t * BATCH + b) * 1024 + dir * HID + c] = hb;
        if (y_node) y_node[((long)b * 256 + t) * 1024 + dir * HID + c] = hb;
        // pack col-pairs and publish via device-coherent atomic (no fence needed)
        u32 mine = (u32)hb;
        u32 other = (u32)__shfl_xor((int)mine, 1);
        if (!(lane & 1))
          atomicExch((u32*)(hout + (long)b * HID + c), mine | (other << 16));
      }
    __asm__ volatile("s_waitcnt vmcnt(0)" ::: "memory");
    if (lane == 0) atomicAdd(myflag, 1u);
  }

#pragma unroll
  for (int cg = 0; cg < 2; cg++)
#pragma unroll
    for (int r = 0; r < 4; r++){
      int b = b0 + q * 4 + r;
      int c = cb * 32 + cg * 16 + col;
      hT[(long)dir * BATCH * HID + (long)b * HID + c] = hold[cg][r];
    }
}

// cat[row][c] += cat[row][512+c] (both bf16), node = yf + yb
__global__ void combine_cat(u16* __restrict__ cat){
  long n = (long)SB * HID;
  long i = (long)blockIdx.x * blockDim.x + threadIdx.x;
  long st = (long)gridDim.x * blockDim.x;
  for (; i < n; i += st){
    long row = i >> 9; int c = (int)(i & 511);
    u16* p = cat + row * 1024;
    p[c] = f2b(b2f(p[c]) + b2f(p[512 + c]));
  }
}

// ---------------- GNN prep ----------------

__global__ __launch_bounds__(64) void deg_kernel(const int* __restrict__ pg, float* __restrict__ dinv){
  int i = blockIdx.x, b = blockIdx.y, lane = threadIdx.x;
  const int* p = pg + ((long)b * 3 + 2) * 65536 + i * 256 + lane * 4;
  int4 v = *(const int4*)p;
  int s = v.x + v.y + v.z + v.w;
  for (int o = 32; o; o >>= 1) s += __shfl_down(s, o);
  if (lane == 0) dinv[b * 256 + i] = 1.f / sqrtf((float)(s + 1));
}

__global__ void an_kernel(const int* __restrict__ pg, const float* __restrict__ dinv, u16* __restrict__ An){
  int j = threadIdx.x, i = blockIdx.x, b = blockIdx.y;
  float a = (float)pg[((long)b * 3 + 2) * 65536 + i * 256 + j] + (i == j ? 1.f : 0.f);
  An[((long)b * 256 + i) * 256 + j] = f2b(a * dinv[b * 256 + i] * dinv[b * 256 + j]);
}

// out[z][c][r] = in[z][r][c]; grid (R/32, C/32, Z); block (32,8)
__global__ void transpose_bf16(const u16* __restrict__ in, long sIn, int ldin,
                               u16* __restrict__ out, long sOut, int R){
  __shared__ u16 tile[32][33];
  const u16* ip = in + (long)blockIdx.z * sIn;
  u16* op = out + (long)blockIdx.z * sOut;
  int r0 = blockIdx.x * 32, c0 = blockIdx.y * 32;
  for (int yy = threadIdx.y; yy < 32; yy += 8)
    tile[yy][threadIdx.x] = ip[(long)(r0 + yy) * ldin + c0 + threadIdx.x];
  __syncthreads();
  for (int yy = threadIdx.y; yy < 32; yy += 8)
    op[(long)(c0 + yy) * R + r0 + threadIdx.x] = tile[threadIdx.x][yy];
}

// ---------------- host ----------------

extern "C" void kernel_launch(void* const* d_in, const int* in_sizes, int n_in,
                              void* d_out, int out_size, void* d_ws, size_t ws_size,
                              hipStream_t stream)
{
  const int* i1 = (const int*)d_in[0];
  const int* i2 = (const int*)d_in[1];
  const int* pg = (const int*)d_in[3];
  const float* e1 = (const float*)d_in[4];
  const float* e2 = (const float*)d_in[5];
  const float* wih[2][2]  = {{(const float*)d_in[6],  (const float*)d_in[10]},
                             {(const float*)d_in[14], (const float*)d_in[18]}};
  const float* whhI[2][2] = {{(const float*)d_in[7],  (const float*)d_in[11]},
                             {(const float*)d_in[15], (const float*)d_in[19]}};
  const float* bihI[2][2] = {{(const float*)d_in[8],  (const float*)d_in[12]},
                             {(const float*)d_in[16], (const float*)d_in[20]}};
  const float* bhhI[2][2] = {{(const float*)d_in[9],  (const float*)d_in[13]},
                             {(const float*)d_in[17], (const float*)d_in[21]}};
  const float* fc1w = (const float*)d_in[22]; const float* fc1b = (const float*)d_in[23];
  const float* fc2w = (const float*)d_in[24]; const float* fc2b = (const float*)d_in[25];
  const float* outw = (const float*)d_in[26]; const float* outb = (const float*)d_in[27];
  float* out = (float*)d_out;

  char* wp = (char*)d_ws;
  auto alloc = [&](size_t bytes) -> void* {
    void* r = (void*)wp; wp += (bytes + 255) & ~(size_t)255; return r;
  };
  const int dins[2] = {192, 1024};

  // ---- UNION region (192 MB): GRU phase = xg[2][SB][GATE]; GNN phase = An/nodeT/t1/nib/cat1
  char* ubase = wp;
  u16* xg = (u16*)alloc((size_t)2 * SB * GATE * 2);              // 201,326,592 B
  u16* An    = (u16*)(ubase);                                    // 16,777,216 B
  u16* nodeT = (u16*)(ubase + 16777216);                         // 33,554,432 B
  u16* t1    = (u16*)(ubase + 50331648);                         // 33,554,432 B
  u16* nib   = (u16*)(ubase + 83886080);                         // 33,554,432 B
  u16* cat1  = (u16*)(ubase + 117440512);                        // 67,108,864 B

  // ---- x1b / cat0 union (64 MB)
  u16* x1b  = (u16*)alloc((size_t)SB * 1024 * 2);
  u16* cat0 = x1b;

  u16* x0b   = (u16*)alloc((size_t)SB * 192 * 2);
  u16* hbf   = (u16*)alloc((size_t)2 * 2 * BATCH * HID * 2);     // [parity][dir][B*H] bf16
  u32* ctr   = (u32*)alloc((size_t)16 * 16 * 4);                 // flags[16 groups][16 slots]
  float* dinv= (float*)alloc((size_t)BATCH * S_LEN * 4);
  u16* wihp[2][2]; u16* whhp[2][2]; float* bihp[2][2]; float* bhhp[2][2];
  for (int l = 0; l < 2; l++)
    for (int d = 0; d < 2; d++) wihp[l][d] = (u16*)alloc((size_t)GATE * dins[l] * 2);
  for (int l = 0; l < 2; l++)
    for (int d = 0; d < 2; d++) whhp[l][d] = (u16*)alloc((size_t)GATE * HID * 2);
  for (int l = 0; l < 2; l++)
    for (int d = 0; d < 2; d++) bihp[l][d] = (float*)alloc((size_t)GATE * 4);
  for (int l = 0; l < 2; l++)
    for (int d = 0; d < 2; d++) bhhp[l][d] = (float*)alloc((size_t)GATE * 4);
  u16* fc1wb = (u16*)alloc((size_t)2 * HID * HID * 2);
  u16* fc2wb = (u16*)alloc((size_t)2 * HID * HID * 2);
  u16* outwb = (u16*)alloc((size_t)2 * HID * 1024 * 2);

  size_t need = (size_t)(wp - (char*)d_ws);
  if (need > ws_size) return;   // clean failure instead of HSA abort

  // ---- weight prep ----
  for (int l = 0; l < 2; l++)
    for (int d = 0; d < 2; d++){
      permute_rows<<<256, 256, 0, stream>>>(wih[l][d], wihp[l][d], dins[l]);
      permute_rows<<<256, 256, 0, stream>>>(whhI[l][d], whhp[l][d], HID);
      permute_bias<<<6, 256, 0, stream>>>(bihI[l][d], bihp[l][d]);
      permute_bias<<<6, 256, 0, stream>>>(bhhI[l][d], bhhp[l][d]);
    }
  cvt_bf16<<<512, 256, 0, stream>>>(fc1w, fc1wb, (long)2 * HID * HID);
  cvt_bf16<<<512, 256, 0, stream>>>(fc2w, fc2wb, (long)2 * HID * HID);
  cvt_bf16<<<512, 256, 0, stream>>>(outw, outwb, (long)2 * HID * 1024);
  embed_kernel<<<SB, 192, 0, stream>>>(i1, i2, e1, e2, x0b);

  auto gemm = [&](const u16* A, int lda, long sAz, const u16* W, int ldw, long sWz,
                  const float* bias, u16* Cb, int ldc, long sCz, float* Cf,
                  int M, int N, int K, int Z, int flags){
    dim3 g(M / 128, N / 128, Z);
    gemm_bt<<<g, 256, 0, stream>>>(A, lda, sAz, W, ldw, sWz, bias, Cb, ldc, sCz, Cf, K, flags);
  };

  // ---- GRU layers (persistent cooperative kernel per layer) ----
  for (int l = 0; l < 2; l++){
    const u16* xin = l ? x1b : x0b; int K = dins[l];
    for (int d = 0; d < 2; d++)
      gemm(xin, K, 0, wihp[l][d], K, 0, bihp[l][d],
           xg + (long)d * SB * GATE, GATE, 0, nullptr, SB, GATE, K, 1, 0);
    // zero parity buffers (h=0 start) + flags
    fill_zero<<<128, 256, 0, stream>>>((float*)hbf, (long)(2 * 2 * BATCH * HID) / 2);
    fill_zero<<<1, 256, 0, stream>>>((float*)ctr, 256);
    const u16* whh_l = whhp[l][0];
    const float* bhh_l = bhhp[l][0];
    u16* ycat = (l == 0) ? x1b : nullptr;
    u16* ynode = (l == 0) ? nullptr : cat0;
    float* hT = out + (long)SB * HID + (long)l * 2 * BATCH * HID;
    void* args[8] = { (void*)&whh_l, (void*)&bhh_l, (void*)&xg, (void*)&hbf,
                      (void*)&ycat, (void*)&ynode, (void*)&hT, (void*)&ctr };
    hipError_t e = hipLaunchCooperativeKernel((const void*)gru_persist, dim3(256), dim3(64),
                                              args, 0, stream);
    (void)e;
  }

  // ---- GNN ----  (xg dead; An/nodeT/t1/nib/cat1 overlay its region)
  combine_cat<<<2048, 256, 0, stream>>>(cat0);
  deg_kernel<<<dim3(256, 128), 64, 0, stream>>>(pg, dinv);
  an_kernel<<<dim3(256, 128), 256, 0, stream>>>(pg, dinv, An);

  u16* cc = cat0; u16* cn = cat1;
  for (int hop = 0; hop < 2; hop++){
    transpose_bf16<<<dim3(8, 16, 128), dim3(32, 8), 0, stream>>>(
        cc, (long)S_LEN * 1024, 1024, nodeT, (long)HID * S_LEN, S_LEN);
    gemm(An, 256, (long)S_LEN * S_LEN, nodeT, 256, (long)HID * S_LEN, nullptr,
         t1, HID, (long)S_LEN * HID, nullptr, S_LEN, HID, S_LEN, BATCH, 0);
    gemm(t1, HID, 0, fc1wb + (long)hop * HID * HID, HID, 0, fc1b + hop * HID,
         nib, HID, 0, nullptr, SB, HID, HID, 1, 1);
    transpose_bf16<<<dim3(8, 16, 128), dim3(32, 8), 0, stream>>>(
        nib, (long)S_LEN * HID, HID, nodeT, (long)HID * S_LEN, S_LEN);
    gemm(An, 256, (long)S_LEN * S_LEN, nodeT, 256, (long)HID * S_LEN, nullptr,
         t1, HID, (long)S_LEN * HID, nullptr, S_LEN, HID, S_LEN, BATCH, 0);
    gemm(t1, HID, 0, fc2wb + (long)hop * HID * HID, HID, 0, fc2b + hop * HID,
         cc + HID, 1024, 0, nullptr, SB, HID, HID, 1, 1);
    gemm(cc, 1024, 0, outwb + (long)hop * HID * 1024, 1024, 0, outb + hop * HID,
         (hop == 1) ? nullptr : cn, 1024, 0, (hop == 1) ? out : nullptr, SB, HID, 1024, 1, 1);
    u16* tmp = cc; cc = cn; cn = tmp;
  }
}

// Round 6
// 4153.837 us; speedup vs baseline: 2.6642x; 1.3474x over previous
//
#include <hip/hip_runtime.h>
#include <hip/hip_bf16.h>

using short8 = __attribute__((ext_vector_type(8))) short;
using f32x4  = __attribute__((ext_vector_type(4))) float;
typedef unsigned short u16;
typedef unsigned int u32;

#define S_LEN 256
#define BATCH 128
#define HID   512
#define GATE  1536
#define SB    32768   // S_LEN*BATCH

static __device__ __forceinline__ u16 f2b(float f){
  union { float f; u32 u; } v; v.f = f;
  u32 r = v.u + 0x7fffu + ((v.u >> 16) & 1u);
  return (u16)(r >> 16);
}
static __device__ __forceinline__ float b2f(u16 h){
  union { u32 u; float f; } v; v.u = ((u32)h) << 16; return v.f;
}
static __device__ __forceinline__ f32x4 mfma16(short8 a, short8 b, f32x4 c){
  return __builtin_amdgcn_mfma_f32_16x16x32_bf16(a, b, c, 0, 0, 0);
}

// coherent (cache-bypass) 16B load: issued async; caller must s_waitcnt before use
static __device__ __forceinline__ void load16_coherent(uint4* dst, const void* p){
  asm volatile("global_load_dwordx4 %0, %1, off sc0 sc1"
               : "=v"(*dst) : "v"(p) : "memory");
}
// coherent (write-through) dword store
static __device__ __forceinline__ void store4_coherent(void* p, u32 v){
  asm volatile("global_store_dword %0, %1, off sc0 sc1"
               :: "v"(p), "v"(v) : "memory");
}
static __device__ __forceinline__ void wait_vm0(){
  asm volatile("s_waitcnt vmcnt(0)" ::: "memory");
}

// ---------------- utility kernels ----------------

__global__ void fill_zero(float* p, long n){
  long i = (long)blockIdx.x * blockDim.x + threadIdx.x;
  long st = (long)gridDim.x * blockDim.x;
  for (; i < n; i += st) p[i] = 0.f;
}

__global__ void cvt_bf16(const float* in, u16* out, long n){
  long i = (long)blockIdx.x * blockDim.x + threadIdx.x;
  long st = (long)gridDim.x * blockDim.x;
  for (; i < n; i += st) out[i] = f2b(in[i]);
}

// gate-row permutation: old row = g*512 + c  ->  new row = 48*(c>>4) + 16*g + (c&15)
__global__ void permute_rows(const float* in, u16* out, int K){
  long n = (long)GATE * K;
  long i = (long)blockIdx.x * blockDim.x + threadIdx.x;
  long st = (long)gridDim.x * blockDim.x;
  for (; i < n; i += st){
    int orow = (int)(i / K); int k = (int)(i - (long)orow * K);
    int g = orow >> 9, c = orow & 511;
    int nrow = ((c >> 4) * 48) + (g << 4) + (c & 15);
    out[(long)nrow * K + k] = f2b(in[i]);
  }
}

__global__ void permute_bias(const float* in, float* out){
  int orow = blockIdx.x * blockDim.x + threadIdx.x;
  if (orow < GATE){
    int g = orow >> 9, c = orow & 511;
    out[((c >> 4) * 48) + (g << 4) + (c & 15)] = in[orow];
  }
}

// x0[s*B+b][0:128]=emb1[i1], [128:192]=emb2[i2] (0 if idx==0), bf16
__global__ void embed_kernel(const int* __restrict__ i1, const int* __restrict__ i2,
                             const float* __restrict__ e1, const float* __restrict__ e2,
                             u16* __restrict__ x0){
  int row = blockIdx.x; int t = threadIdx.x;
  float v;
  if (t < 128) v = e1[(long)i1[row] * 128 + t];
  else { int ix = i2[row]; v = ix ? e2[(long)ix * 64 + (t - 128)] : 0.f; }
  x0[(long)row * 192 + t] = f2b(v);
}

// ---------------- generic bf16 MFMA GEMM: C = A[M,K] * W[N,K]^T (+bias)(+relu) ----------------
__global__ __launch_bounds__(256) void gemm_bt(
    const u16* __restrict__ A, int lda, long sAz,
    const u16* __restrict__ W, int ldw, long sWz,
    const float* __restrict__ bias,
    u16* __restrict__ Cb, int ldc, long sCz,
    float* __restrict__ Cf,       // optional f32 out, (b,s)->(s,b) transposed, ld 512
    int K, int flags)             // bit0 = relu
{
  __shared__ u16 As[128 * 40];
  __shared__ u16 Ws[128 * 40];
  const int tid = threadIdx.x;
  const int m0 = blockIdx.x * 128, n0 = blockIdx.y * 128;
  const long z = blockIdx.z;
  const u16* Ab = A + z * sAz;
  const u16* Wb = W + z * sWz;
  const int r0 = tid >> 2, kg = (tid & 3) * 8;
  const int lane = tid & 63, w = tid >> 6;
  const int wr = w >> 1, wc = w & 1;
  const int col = lane & 15, q = lane >> 4;
  f32x4 acc[4][4];
#pragma unroll
  for (int i = 0; i < 4; i++)
#pragma unroll
    for (int j = 0; j < 4; j++) acc[i][j] = (f32x4){0.f, 0.f, 0.f, 0.f};

  for (int k0 = 0; k0 < K; k0 += 32){
    uint4 a0 = *(const uint4*)(Ab + (long)(m0 + r0) * lda + k0 + kg);
    uint4 a1 = *(const uint4*)(Ab + (long)(m0 + r0 + 64) * lda + k0 + kg);
    uint4 w0 = *(const uint4*)(Wb + (long)(n0 + r0) * ldw + k0 + kg);
    uint4 w1 = *(const uint4*)(Wb + (long)(n0 + r0 + 64) * ldw + k0 + kg);
    __syncthreads();
    *(uint4*)(As + r0 * 40 + kg) = a0;
    *(uint4*)(As + (r0 + 64) * 40 + kg) = a1;
    *(uint4*)(Ws + r0 * 40 + kg) = w0;
    *(uint4*)(Ws + (r0 + 64) * 40 + kg) = w1;
    __syncthreads();
    short8 af[4], bf[4];
#pragma unroll
    for (int i = 0; i < 4; i++) af[i] = *(const short8*)(As + (wr * 64 + i * 16 + col) * 40 + q * 8);
#pragma unroll
    for (int j = 0; j < 4; j++) bf[j] = *(const short8*)(Ws + (wc * 64 + j * 16 + col) * 40 + q * 8);
#pragma unroll
    for (int i = 0; i < 4; i++)
#pragma unroll
      for (int j = 0; j < 4; j++)
        acc[i][j] = mfma16(af[i], bf[j], acc[i][j]);
  }

#pragma unroll
  for (int i = 0; i < 4; i++)
#pragma unroll
    for (int j = 0; j < 4; j++){
      int n = n0 + wc * 64 + j * 16 + col;
      float bv = bias ? bias[n] : 0.f;
#pragma unroll
      for (int r = 0; r < 4; r++){
        int m = m0 + wr * 64 + i * 16 + q * 4 + r;
        float v = acc[i][j][r] + bv;
        if (flags & 1) v = fmaxf(v, 0.f);
        if (Cb) Cb[z * sCz + (long)m * ldc + n] = f2b(v);
        if (Cf){ int s = m & 255, b = m >> 8; Cf[((long)s * 128 + b) * 512 + n] = v; }
      }
    }
}

// ---------------- persistent GRU layer (cooperative launch) ----------------
// grid 256 x 64: dir = bid>>7; r=bid&127: cb = r>>3 (16 blocks of 32 channels),
// bt = r&7 (8 tiles of 16 batches). Sync group = (dir,bt): 16 groups x 16 slots.
// h exchange: coherent (sc0 sc1) cache-bypass stores/loads -- coalescing, no atomics,
// no cache-maintenance fences. Barrier: per-block monotone flag + wide poll.
__global__ __launch_bounds__(64) void gru_persist(
    const u16* __restrict__ whh,    // [2][GATE*HID] permuted bf16 (dirs adjacent)
    const float* __restrict__ bhh,  // [2][GATE] permuted
    const u16* __restrict__ xg,     // [2][SB*GATE] bf16 (permuted cols)
    u16* __restrict__ hbf,          // [2 parity][2 dir][BATCH*HID] bf16, parity0 zeroed
    u16* __restrict__ y_cat,        // layer0: x1 [SB,1024] seq-major, else null
    u16* __restrict__ y_node,       // layer1: cat0 [b][s][dir*512+c], else null
    float* __restrict__ hT,         // final hidden out [2 dir][BATCH*HID] f32
    u32* __restrict__ flags)        // [16 groups][16 slots] u32, zeroed
{
  const int bid = blockIdx.x;
  const int dir = bid >> 7, r7 = bid & 127;
  const int cb = r7 >> 3, bt = r7 & 7, b0 = bt * 16;
  const int lane = threadIdx.x, col = lane & 15, q = lane >> 4;
  u32* gflag = flags + (dir * 8 + bt) * 16;
  u32* myflag = gflag + cb;

  __shared__ u16 Ws[96 * 520];   // 96 rows (2 col-groups x 3 gates x 16), pad-520
  {
    const u16* Wd = whh + (long)dir * GATE * HID + (long)(96 * cb) * HID;
    for (int i = lane; i < 96 * 64; i += 64){
      int row = i >> 6, k8 = (i & 63) << 3;
      *(short8*)(Ws + row * 520 + k8) = *(const short8*)(Wd + (long)row * HID + k8);
    }
  }
  __syncthreads();

  const u16* xgd = xg + (long)dir * SB * GATE;
  const float* bh = bhh + dir * GATE;
  float bhv[2][3];
#pragma unroll
  for (int cg = 0; cg < 2; cg++)
#pragma unroll
    for (int g = 0; g < 3; g++)
      bhv[cg][g] = bh[48 * (2 * cb + cg) + 16 * g + col];

  float hold[2][4];
#pragma unroll
  for (int cg = 0; cg < 2; cg++)
#pragma unroll
    for (int r = 0; r < 4; r++) hold[cg][r] = 0.f;

  for (int s = 0; s < 256; s++){
    const int t = dir ? (255 - s) : s;
    // prefetch xg slice for this step (issued before the spin)
    u16 xv[2][4][3];
#pragma unroll
    for (int cg = 0; cg < 2; cg++)
#pragma unroll
      for (int r = 0; r < 4; r++){
        const u16* xp = xgd + ((long)t * BATCH + (b0 + q * 4 + r)) * GATE + 48 * (2 * cb + cg);
#pragma unroll
        for (int g = 0; g < 3; g++) xv[cg][r][g] = xp[16 * g + col];
      }
    if (s){
      const u32 tgt = (u32)s;
      for (;;){
        u32 v = __hip_atomic_load(gflag + (lane & 15), __ATOMIC_RELAXED, __HIP_MEMORY_SCOPE_AGENT);
        if (__ballot(v >= tgt) == ~0ull) break;
        __builtin_amdgcn_s_sleep(1);
      }
    }
    const u16* hin = hbf + ((long)((s & 1) * 2 + dir)) * (BATCH * HID);
    u16* hout = hbf + ((long)(((s & 1) ^ 1) * 2 + dir)) * (BATCH * HID);

    // issue all 16 coherent h loads (16B/lane each), single wait, then MFMA
    uint4 hreg[16];
#pragma unroll
    for (int kk = 0; kk < 16; kk++)
      load16_coherent(&hreg[kk], hin + (long)(b0 + col) * HID + kk * 32 + q * 8);
    wait_vm0();

    f32x4 acc[6];
#pragma unroll
    for (int tl = 0; tl < 6; tl++) acc[tl] = (f32x4){0.f, 0.f, 0.f, 0.f};

#pragma unroll
    for (int kk = 0; kk < 16; kk++){
      short8 a8 = *(const short8*)&hreg[kk];
#pragma unroll
      for (int tl = 0; tl < 6; tl++){
        short8 bfr = *(const short8*)(Ws + (tl * 16 + col) * 520 + kk * 32 + q * 8);
        acc[tl] = mfma16(a8, bfr, acc[tl]);
      }
    }

#pragma unroll
    for (int cg = 0; cg < 2; cg++)
#pragma unroll
      for (int r = 0; r < 4; r++){
        int b = b0 + q * 4 + r;
        int c = cb * 32 + cg * 16 + col;
        float xr = b2f(xv[cg][r][0]);
        float xz = b2f(xv[cg][r][1]);
        float xn = b2f(xv[cg][r][2]);
        float gr = 1.f / (1.f + expf(-(xr + acc[cg * 3 + 0][r] + bhv[cg][0])));
        float gz = 1.f / (1.f + expf(-(xz + acc[cg * 3 + 1][r] + bhv[cg][1])));
        float gn = tanhf(xn + gr * (acc[cg * 3 + 2][r] + bhv[cg][2]));
        float hnew = (1.f - gz) * gn + gz * hold[cg][r];
        hold[cg][r] = hnew;
        u16 hb = f2b(hnew);
        if (y_cat)  y_cat[((long)t * BATCH + b) * 1024 + dir * HID + c] = hb;
        if (y_node) y_node[((long)b * 256 + t) * 1024 + dir * HID + c] = hb;
        // pack col-pairs, publish via coherent write-through dword store
        u32 mine = (u32)hb;
        u32 other = (u32)__shfl_xor((int)mine, 1);
        if (!(lane & 1))
          store4_coherent(hout + (long)b * HID + c, mine | (other << 16));
      }
    wait_vm0();   // h stores at coherence point before flag bump
    if (lane == 0) atomicAdd(myflag, 1u);
  }

#pragma unroll
  for (int cg = 0; cg < 2; cg++)
#pragma unroll
    for (int r = 0; r < 4; r++){
      int b = b0 + q * 4 + r;
      int c = cb * 32 + cg * 16 + col;
      hT[(long)dir * BATCH * HID + (long)b * HID + c] = hold[cg][r];
    }
}

// cat[row][c] += cat[row][512+c] (both bf16), node = yf + yb
__global__ void combine_cat(u16* __restrict__ cat){
  long n = (long)SB * HID;
  long i = (long)blockIdx.x * blockDim.x + threadIdx.x;
  long st = (long)gridDim.x * blockDim.x;
  for (; i < n; i += st){
    long row = i >> 9; int c = (int)(i & 511);
    u16* p = cat + row * 1024;
    p[c] = f2b(b2f(p[c]) + b2f(p[512 + c]));
  }
}

// ---------------- GNN prep ----------------

__global__ __launch_bounds__(64) void deg_kernel(const int* __restrict__ pg, float* __restrict__ dinv){
  int i = blockIdx.x, b = blockIdx.y, lane = threadIdx.x;
  const int* p = pg + ((long)b * 3 + 2) * 65536 + i * 256 + lane * 4;
  int4 v = *(const int4*)p;
  int s = v.x + v.y + v.z + v.w;
  for (int o = 32; o; o >>= 1) s += __shfl_down(s, o);
  if (lane == 0) dinv[b * 256 + i] = 1.f / sqrtf((float)(s + 1));
}

__global__ void an_kernel(const int* __restrict__ pg, const float* __restrict__ dinv, u16* __restrict__ An){
  int j = threadIdx.x, i = blockIdx.x, b = blockIdx.y;
  float a = (float)pg[((long)b * 3 + 2) * 65536 + i * 256 + j] + (i == j ? 1.f : 0.f);
  An[((long)b * 256 + i) * 256 + j] = f2b(a * dinv[b * 256 + i] * dinv[b * 256 + j]);
}

// out[z][c][r] = in[z][r][c]; grid (R/32, C/32, Z); block (32,8)
__global__ void transpose_bf16(const u16* __restrict__ in, long sIn, int ldin,
                               u16* __restrict__ out, long sOut, int R){
  __shared__ u16 tile[32][33];
  const u16* ip = in + (long)blockIdx.z * sIn;
  u16* op = out + (long)blockIdx.z * sOut;
  int r0 = blockIdx.x * 32, c0 = blockIdx.y * 32;
  for (int yy = threadIdx.y; yy < 32; yy += 8)
    tile[yy][threadIdx.x] = ip[(long)(r0 + yy) * ldin + c0 + threadIdx.x];
  __syncthreads();
  for (int yy = threadIdx.y; yy < 32; yy += 8)
    op[(long)(c0 + yy) * R + r0 + threadIdx.x] = tile[threadIdx.x][yy];
}

// ---------------- host ----------------

extern "C" void kernel_launch(void* const* d_in, const int* in_sizes, int n_in,
                              void* d_out, int out_size, void* d_ws, size_t ws_size,
                              hipStream_t stream)
{
  const int* i1 = (const int*)d_in[0];
  const int* i2 = (const int*)d_in[1];
  const int* pg = (const int*)d_in[3];
  const float* e1 = (const float*)d_in[4];
  const float* e2 = (const float*)d_in[5];
  const float* wih[2][2]  = {{(const float*)d_in[6],  (const float*)d_in[10]},
                             {(const float*)d_in[14], (const float*)d_in[18]}};
  const float* whhI[2][2] = {{(const float*)d_in[7],  (const float*)d_in[11]},
                             {(const float*)d_in[15], (const float*)d_in[19]}};
  const float* bihI[2][2] = {{(const float*)d_in[8],  (const float*)d_in[12]},
                             {(const float*)d_in[16], (const float*)d_in[20]}};
  const float* bhhI[2][2] = {{(const float*)d_in[9],  (const float*)d_in[13]},
                             {(const float*)d_in[17], (const float*)d_in[21]}};
  const float* fc1w = (const float*)d_in[22]; const float* fc1b = (const float*)d_in[23];
  const float* fc2w = (const float*)d_in[24]; const float* fc2b = (const float*)d_in[25];
  const float* outw = (const float*)d_in[26]; const float* outb = (const float*)d_in[27];
  float* out = (float*)d_out;

  char* wp = (char*)d_ws;
  auto alloc = [&](size_t bytes) -> void* {
    void* r = (void*)wp; wp += (bytes + 255) & ~(size_t)255; return r;
  };
  const int dins[2] = {192, 1024};

  // ---- UNION region (192 MB): GRU phase = xg[2][SB][GATE]; GNN phase = An/nodeT/t1/nib/cat1
  char* ubase = wp;
  u16* xg = (u16*)alloc((size_t)2 * SB * GATE * 2);              // 201,326,592 B
  u16* An    = (u16*)(ubase);                                    // 16,777,216 B
  u16* nodeT = (u16*)(ubase + 16777216);                         // 33,554,432 B
  u16* t1    = (u16*)(ubase + 50331648);                         // 33,554,432 B
  u16* nib   = (u16*)(ubase + 83886080);                         // 33,554,432 B
  u16* cat1  = (u16*)(ubase + 117440512);                        // 67,108,864 B

  // ---- x1b / cat0 union (64 MB)
  u16* x1b  = (u16*)alloc((size_t)SB * 1024 * 2);
  u16* cat0 = x1b;

  u16* x0b   = (u16*)alloc((size_t)SB * 192 * 2);
  u16* hbf   = (u16*)alloc((size_t)2 * 2 * BATCH * HID * 2);     // [parity][dir][B*H] bf16
  u32* ctr   = (u32*)alloc((size_t)16 * 16 * 4);                 // flags[16 groups][16 slots]
  float* dinv= (float*)alloc((size_t)BATCH * S_LEN * 4);
  u16* wihp[2][2]; u16* whhp[2][2]; float* bihp[2][2]; float* bhhp[2][2];
  for (int l = 0; l < 2; l++)
    for (int d = 0; d < 2; d++) wihp[l][d] = (u16*)alloc((size_t)GATE * dins[l] * 2);
  for (int l = 0; l < 2; l++)
    for (int d = 0; d < 2; d++) whhp[l][d] = (u16*)alloc((size_t)GATE * HID * 2);
  for (int l = 0; l < 2; l++)
    for (int d = 0; d < 2; d++) bihp[l][d] = (float*)alloc((size_t)GATE * 4);
  for (int l = 0; l < 2; l++)
    for (int d = 0; d < 2; d++) bhhp[l][d] = (float*)alloc((size_t)GATE * 4);
  u16* fc1wb = (u16*)alloc((size_t)2 * HID * HID * 2);
  u16* fc2wb = (u16*)alloc((size_t)2 * HID * HID * 2);
  u16* outwb = (u16*)alloc((size_t)2 * HID * 1024 * 2);

  size_t need = (size_t)(wp - (char*)d_ws);
  if (need > ws_size) return;   // clean failure instead of HSA abort

  // ---- weight prep ----
  for (int l = 0; l < 2; l++)
    for (int d = 0; d < 2; d++){
      permute_rows<<<256, 256, 0, stream>>>(wih[l][d], wihp[l][d], dins[l]);
      permute_rows<<<256, 256, 0, stream>>>(whhI[l][d], whhp[l][d], HID);
      permute_bias<<<6, 256, 0, stream>>>(bihI[l][d], bihp[l][d]);
      permute_bias<<<6, 256, 0, stream>>>(bhhI[l][d], bhhp[l][d]);
    }
  cvt_bf16<<<512, 256, 0, stream>>>(fc1w, fc1wb, (long)2 * HID * HID);
  cvt_bf16<<<512, 256, 0, stream>>>(fc2w, fc2wb, (long)2 * HID * HID);
  cvt_bf16<<<512, 256, 0, stream>>>(outw, outwb, (long)2 * HID * 1024);
  embed_kernel<<<SB, 192, 0, stream>>>(i1, i2, e1, e2, x0b);

  auto gemm = [&](const u16* A, int lda, long sAz, const u16* W, int ldw, long sWz,
                  const float* bias, u16* Cb, int ldc, long sCz, float* Cf,
                  int M, int N, int K, int Z, int flags){
    dim3 g(M / 128, N / 128, Z);
    gemm_bt<<<g, 256, 0, stream>>>(A, lda, sAz, W, ldw, sWz, bias, Cb, ldc, sCz, Cf, K, flags);
  };

  // ---- GRU layers (persistent cooperative kernel per layer) ----
  for (int l = 0; l < 2; l++){
    const u16* xin = l ? x1b : x0b; int K = dins[l];
    for (int d = 0; d < 2; d++)
      gemm(xin, K, 0, wihp[l][d], K, 0, bihp[l][d],
           xg + (long)d * SB * GATE, GATE, 0, nullptr, SB, GATE, K, 1, 0);
    // zero parity buffers (h=0 start) + flags
    fill_zero<<<128, 256, 0, stream>>>((float*)hbf, (long)(2 * 2 * BATCH * HID) / 2);
    fill_zero<<<1, 256, 0, stream>>>((float*)ctr, 256);
    const u16* whh_l = whhp[l][0];
    const float* bhh_l = bhhp[l][0];
    u16* ycat = (l == 0) ? x1b : nullptr;
    u16* ynode = (l == 0) ? nullptr : cat0;
    float* hT = out + (long)SB * HID + (long)l * 2 * BATCH * HID;
    void* args[8] = { (void*)&whh_l, (void*)&bhh_l, (void*)&xg, (void*)&hbf,
                      (void*)&ycat, (void*)&ynode, (void*)&hT, (void*)&ctr };
    hipError_t e = hipLaunchCooperativeKernel((const void*)gru_persist, dim3(256), dim3(64),
                                              args, 0, stream);
    (void)e;
  }

  // ---- GNN ----  (xg dead; An/nodeT/t1/nib/cat1 overlay its region)
  combine_cat<<<2048, 256, 0, stream>>>(cat0);
  deg_kernel<<<dim3(256, 128), 64, 0, stream>>>(pg, dinv);
  an_kernel<<<dim3(256, 128), 256, 0, stream>>>(pg, dinv, An);

  u16* cc = cat0; u16* cn = cat1;
  for (int hop = 0; hop < 2; hop++){
    transpose_bf16<<<dim3(8, 16, 128), dim3(32, 8), 0, stream>>>(
        cc, (long)S_LEN * 1024, 1024, nodeT, (long)HID * S_LEN, S_LEN);
    gemm(An, 256, (long)S_LEN * S_LEN, nodeT, 256, (long)HID * S_LEN, nullptr,
         t1, HID, (long)S_LEN * HID, nullptr, S_LEN, HID, S_LEN, BATCH, 0);
    gemm(t1, HID, 0, fc1wb + (long)hop * HID * HID, HID, 0, fc1b + hop * HID,
         nib, HID, 0, nullptr, SB, HID, HID, 1, 1);
    transpose_bf16<<<dim3(8, 16, 128), dim3(32, 8), 0, stream>>>(
        nib, (long)S_LEN * HID, HID, nodeT, (long)HID * S_LEN, S_LEN);
    gemm(An, 256, (long)S_LEN * S_LEN, nodeT, 256, (long)HID * S_LEN, nullptr,
         t1, HID, (long)S_LEN * HID, nullptr, S_LEN, HID, S_LEN, BATCH, 0);
    gemm(t1, HID, 0, fc2wb + (long)hop * HID * HID, HID, 0, fc2b + hop * HID,
         cc + HID, 1024, 0, nullptr, SB, HID, HID, 1, 1);
    gemm(cc, 1024, 0, outwb + (long)hop * HID * 1024, 1024, 0, outb + hop * HID,
         (hop == 1) ? nullptr : cn, 1024, 0, (hop == 1) ? out : nullptr, SB, HID, 1024, 1, 1);
    u16* tmp = cc; cc = cn; cn = tmp;
  }
}